// Round 1
// baseline (285.521 us; speedup 1.0000x reference)
//
#include <hip/hip_runtime.h>
#include <hip/hip_bf16.h>

#define N_ROWS 8192
#define D_DIM  4096
#define E_DIM  64
#define BK     256               // K elements per staged chunk
#define NCHUNK (D_DIM / BK)      // 16
#define RB     (BK * 2)          // 512 bytes per row per chunk

typedef __attribute__((ext_vector_type(8))) short  short8;
typedef __attribute__((ext_vector_type(4))) float  floatx4;
typedef __attribute__((ext_vector_type(8))) float  float8;

// async global->LDS, 16B per lane; LDS dest is wave-uniform base + lane*16
__device__ inline void gload16(const void* g, void* l) {
  __builtin_amdgcn_global_load_lds(
      (const __attribute__((address_space(1))) void*)g,
      (__attribute__((address_space(3))) void*)l, 16, 0, 0);
}

// Split an fp32 vector into hi (RNE bf16) + lo (chopped bf16 of remainder).
__device__ inline void cvt_split(const float8& f, short8& hi, short8& lo) {
#pragma unroll
  for (int j = 0; j < 8; ++j) {
    float x = f[j];
    unsigned int u  = __builtin_bit_cast(unsigned int, x);
    unsigned int rh = (u + 0x7FFFu + ((u >> 16) & 1u)) >> 16;  // RNE to bf16
    hi[j] = (short)rh;
    float hf = __builtin_bit_cast(float, rh << 16);
    float lf = x - hf;
    unsigned int ul = __builtin_bit_cast(unsigned int, lf);
    lo[j] = (short)(ul >> 16);                                  // chop
  }
}

// Stage one BK-chunk: x tile 32 rows x 512B (16KB), W tile 64 rows x 512B
// (32KB). LDS dest is LINEAR in thread order (global_load_lds requirement);
// the XOR bank-swizzle is applied to the GLOBAL source address instead
// (rule #21: linear dest + inverse-swizzled source + swizzled read).
__device__ inline void stage_tiles(const char* __restrict__ xb,
                                   const char* __restrict__ wb,
                                   char* xd, char* wd,
                                   int r0, int tid, int wave, size_t kby) {
#pragma unroll
  for (int h = 0; h < 2; ++h) {
    int L = h * 8192 + tid * 16;          // byte position in linear x tile
    int row = L >> 9, colb = L & 511;
    gload16(xb + (size_t)(r0 + row) * (D_DIM * 2) + kby +
                (colb ^ ((row & 7) << 4)),
            xd + h * 8192 + (wave << 10));
  }
#pragma unroll
  for (int h = 0; h < 4; ++h) {
    int L = h * 8192 + tid * 16;          // byte position in linear W tile
    int row = L >> 9, colb = L & 511;
    gload16(wb + (size_t)row * (D_DIM * 2) + kby +
                (colb ^ ((row & 7) << 4)),
            wd + h * 8192 + (wave << 10));
  }
}

// ---------------------------------------------------------------------------
// Fused router: 256 blocks x 512 threads. Block = 32 rows, all 64 experts.
// 8 waves: wave w -> row tile (w&1)*16, expert tile (w>>1)*16.
//
// bf16 path: double-buffered global_load_lds staging (BK=256), XOR-swizzled
// LDS layout, ds_read_b128 fragments, MFMA inner loop. K-chunk start rotated
// per block to decorrelate the 8KB-strided row addresses across the grid.
// fp32 fallback path: previous register-direct split-bf16 loop (unchanged).
// ---------------------------------------------------------------------------
__global__ __launch_bounds__(512) void router_kernel(
    const void* __restrict__ xv, const void* __restrict__ wv,
    const void* __restrict__ bv, float* __restrict__ out) {
  __shared__ __align__(16) char xsm[2][32 * RB];   // 2 x 16 KB
  __shared__ __align__(16) char wsm[2][64 * RB];   // 2 x 32 KB
  __shared__ float lg[32][E_DIM + 4];              // +4 pad
  __shared__ int   sflag;

  const int tid = threadIdx.x;

  // ---- inline dtype probe (wave 0 only) ----
  if (tid < 64) {
    unsigned int v = ((const unsigned int*)xv)[(size_t)tid * 997];
    unsigned int e = (v >> 7) & 0xFFu;   // exponent field of low-16 as bf16
    unsigned long long m = __ballot(e >= 100u && e <= 140u);
    if (tid == 0) sflag = (__popcll(m) > 32) ? 1 : 0;
  }
  __syncthreads();
  const int isbf = sflag;

  const int wave = tid >> 6;
  const int lane = tid & 63;
  const int lm   = lane & 15;           // A: row-in-tile  B: expert-in-tile
  const int kb   = (lane >> 4) << 4;    // BYTE offset of lane's 8 bf16 in 64B k-step
  const int rt   = wave & 1;            // row tile (0/1)
  const int e0   = (wave >> 1) << 4;    // expert tile base
  const int r0   = blockIdx.x << 5;     // 32 rows per block
  const int arow = rt * 16 + lm;        // x row within block tile (0..31)
  const int brow = e0 + lm;             // W row (0..63)

  floatx4 acc = {0.f, 0.f, 0.f, 0.f};

  if (isbf) {
    const char* xb = (const char*)xv;
    const char* wb = (const char*)wv;
    const int c0   = blockIdx.x & (NCHUNK - 1);   // rotate K start per block
    const int aswz = (arow & 7) << 4;
    const int bswz = (brow & 7) << 4;

    stage_tiles(xb, wb, xsm[0], wsm[0], r0, tid, wave, (size_t)c0 * RB);
    __syncthreads();   // compiler drains vmcnt(0) before s_barrier

#pragma unroll 2
    for (int i = 0; i < NCHUNK; ++i) {
      if (i + 1 < NCHUNK) {
        int ci = (c0 + i + 1) & (NCHUNK - 1);
        stage_tiles(xb, wb, xsm[(i + 1) & 1], wsm[(i + 1) & 1],
                    r0, tid, wave, (size_t)ci * RB);
      }
      const char* xs = xsm[i & 1];
      const char* ws = wsm[i & 1];
#pragma unroll
      for (int kk = 0; kk < 8; ++kk) {
        int c = (kk << 6) + kb;
        short8 a = *(const short8*)(xs + (arow << 9) + (c ^ aswz));
        short8 b = *(const short8*)(ws + (brow << 9) + (c ^ bswz));
        acc = __builtin_amdgcn_mfma_f32_16x16x32_bf16(a, b, acc, 0, 0, 0);
      }
      __syncthreads();   // waits next-chunk loads AND releases this buffer
    }
  } else {
    // fp32 fallback: register-direct split-bf16 (previous verified path)
    const int lk = kb >> 1;  // element offset
    const float* xp = (const float*)xv + (size_t)(r0 + arow) * D_DIM + lk;
    const float* wp = (const float*)wv + (size_t)brow * D_DIM + lk;
    for (int k = 0; k < D_DIM; k += 32) {
      float8 af = *(const float8*)(xp + k);
      float8 bf = *(const float8*)(wp + k);
      short8 ah, al, bh, bl;
      cvt_split(af, ah, al);
      cvt_split(bf, bh, bl);
      acc = __builtin_amdgcn_mfma_f32_16x16x32_bf16(ah, bh, acc, 0, 0, 0);
      acc = __builtin_amdgcn_mfma_f32_16x16x32_bf16(ah, bl, acc, 0, 0, 0);
      acc = __builtin_amdgcn_mfma_f32_16x16x32_bf16(al, bh, acc, 0, 0, 0);
    }
  }

  // C/D layout (m89-verified): col = lane&15 (expert), row = (lane>>4)*4 + reg
  {
    const int col   = brow;                        // e0 + lm
    const int rbase = rt * 16 + ((lane >> 4) << 2);
#pragma unroll
    for (int r = 0; r < 4; ++r) lg[rbase + r][col] = acc[r];
  }
  __syncthreads();

  if (tid < 32) {
    const int row = tid;
    float m1 = -3.4e38f, m2 = -3.4e38f;
    int   i1 = 0, i2 = 0;
    for (int e = 0; e < E_DIM; ++e) {
      float be = isbf ? __bfloat162float(((const __hip_bfloat16*)bv)[e])
                      : ((const float*)bv)[e];
      float l = lg[row][e] + be;
      if (l > m1)      { m2 = m1; i2 = i1; m1 = l; i1 = e; }
      else if (l > m2) { m2 = l;  i2 = e; }
    }
    float s = 0.f;
    for (int e = 0; e < E_DIM; ++e) {
      float be = isbf ? __bfloat162float(((const __hip_bfloat16*)bv)[e])
                      : ((const float*)bv)[e];
      s += expf(lg[row][e] + be - m1);
    }
    const int gr = r0 + row;
    // outputs concatenated flat: [N*2 indices][N*2 weights], all as float32
    out[2 * gr]                  = (float)i1;
    out[2 * gr + 1]              = (float)i2;
    out[2 * N_ROWS + 2 * gr]     = 1.0f / s;                 // exp(m1-m1)/s
    out[2 * N_ROWS + 2 * gr + 1] = expf(m2 - m1) / s;
  }
}

extern "C" void kernel_launch(void* const* d_in, const int* in_sizes, int n_in,
                              void* d_out, int out_size, void* d_ws, size_t ws_size,
                              hipStream_t stream) {
  (void)in_sizes; (void)n_in; (void)out_size; (void)d_ws; (void)ws_size;
  router_kernel<<<dim3(N_ROWS / 32), dim3(512), 0, stream>>>(
      d_in[0], d_in[1], d_in[2], (float*)d_out);
}

// Round 2
// 225.302 us; speedup vs baseline: 1.2673x; 1.2673x over previous
//
#include <hip/hip_runtime.h>
#include <hip/hip_bf16.h>

#define N_ROWS 8192
#define D_DIM  4096
#define E_DIM  64
#define BKF    128               // fp32 K elems per staged chunk
#define NCHF   (D_DIM / BKF)     // 32 chunks

typedef __attribute__((ext_vector_type(8))) short  short8;
typedef __attribute__((ext_vector_type(4))) float  floatx4;
typedef __attribute__((ext_vector_type(8))) float  float8;

// Split an fp32 vector into hi (RNE bf16) + lo (chopped bf16 of remainder).
// Same math as the previously verified kernel -> identical numerics.
__device__ inline void cvt_split(const float8& f, short8& hi, short8& lo) {
#pragma unroll
  for (int j = 0; j < 8; ++j) {
    float x = f[j];
    unsigned int u  = __builtin_bit_cast(unsigned int, x);
    unsigned int rh = (u + 0x7FFFu + ((u >> 16) & 1u)) >> 16;  // RNE to bf16
    hi[j] = (short)rh;
    float hf = __builtin_bit_cast(float, rh << 16);
    float lf = x - hf;
    unsigned int ul = __builtin_bit_cast(unsigned int, lf);
    lo[j] = (short)(ul >> 16);                                  // chop
  }
}

// ---------------------------------------------------------------------------
// Fused router: 256 blocks x 512 threads. Block = 32 rows, all 64 experts.
// 8 waves: wave w -> row tile (w&1)*16, expert tile (w>>1)*16.
//
// INPUT IS FP32 (probe-verified over two rounds; in_npz 125MB = fp32 x).
// fp32 main path: reg-staged pipeline with CONVERSION FUSED INTO STAGING.
//   Each chunk (BK=128): coalesced float8 global loads -> cvt_split in regs
//   -> swizzled ds_write_b128 into split-bf16 LDS planes (hi|lo for x and W).
//   Each element converted ONCE per block (was 4x for x, 512x for W grid-wide
//   per-fragment). Compute loop is pure ds_read_b128 + 3 MFMAs per K-step.
//   Double-buffered, 1 barrier/chunk; loads for chunk i+1 issued before
//   compute of chunk i (T14 order) so HBM latency hides under MFMA+cvt.
//   LDS slot swizzle (slot ^= row&7) on both write and read: 16-way -> 2-way.
// bf16 fallback: register-direct MFMA loop (unexercised; kept for safety).
//
// Buffer layout (bytes, per 48KB buffer):
//   xh [32][128]bf16 @ 0      (8K)   xl @ 8192   (8K)
//   wh [64][128]bf16 @ 16384  (16K)  wl @ 32768  (16K)
// row stride 256B; 16B slot s of row r stored at slot s^(r&7).
// ---------------------------------------------------------------------------
__global__ __launch_bounds__(512) void router_kernel(
    const void* __restrict__ xv, const void* __restrict__ wv,
    const void* __restrict__ bv, float* __restrict__ out) {
  __shared__ __align__(16) char sm[2][49152];     // 96 KB double-buffered
  __shared__ float lg[32][E_DIM + 4];             // +4 pad
  __shared__ int   sflag;

  const int tid = threadIdx.x;

  // ---- inline dtype probe (wave 0 only) ----
  if (tid < 64) {
    unsigned int v = ((const unsigned int*)xv)[(size_t)tid * 997];
    unsigned int e = (v >> 7) & 0xFFu;   // exponent field of low-16 as bf16
    unsigned long long m = __ballot(e >= 100u && e <= 140u);
    if (tid == 0) sflag = (__popcll(m) > 32) ? 1 : 0;
  }
  __syncthreads();
  const int isbf = sflag;

  const int wave = tid >> 6;
  const int lane = tid & 63;
  const int lm   = lane & 15;           // A: row-in-tile  B: expert-in-tile
  const int t4   = lane >> 4;           // k sub-slot within 32-wide K step
  const int rt   = wave & 1;            // row tile (0/1)
  const int e0   = (wave >> 1) << 4;    // expert tile base
  const int r0   = blockIdx.x << 5;     // 32 rows per block
  const int arow = rt * 16 + lm;        // x row within block tile (0..31)
  const int brow = e0 + lm;             // W row (0..63)

  floatx4 acc = {0.f, 0.f, 0.f, 0.f};

  if (!isbf) {
    // ---------------- fp32 main path ----------------
    // staging geometry: thread -> 1 x-seg + 2 W-segs (float8 = 32B each)
    const int srow = tid >> 4;          // 0..31
    const int s8   = tid & 15;          // float8 seg within row == 16B bf16 slot
    const float* xg  = (const float*)xv + (size_t)(r0 + srow) * D_DIM + s8 * 8;
    const float* wg0 = (const float*)wv + (size_t)srow * D_DIM + s8 * 8;
    const float* wg1 = wg0 + (size_t)32 * D_DIM;
    const int wx = srow * 256 + ((s8 ^ (srow & 7)) << 4);  // swizzled write off

    // fragment read bases
    const int axr = arow & 7, bxr = brow & 7;
    const int ra  = arow * 256;            // xh; xl = +8192
    const int rb  = 16384 + brow * 256;    // wh; wl = +16384

    // prologue: stage chunk 0
    {
      float8 fx = *(const float8*)xg;
      float8 f0 = *(const float8*)wg0;
      float8 f1 = *(const float8*)wg1;
      char* d = sm[0];
      short8 h, l;
      cvt_split(fx, h, l);
      *(short8*)(d + wx)         = h;  *(short8*)(d + 8192  + wx) = l;
      cvt_split(f0, h, l);
      *(short8*)(d + 16384 + wx) = h;  *(short8*)(d + 32768 + wx) = l;
      cvt_split(f1, h, l);
      *(short8*)(d + 24576 + wx) = h;  *(short8*)(d + 40960 + wx) = l;
    }
    __syncthreads();

    for (int i = 0; i < NCHF; ++i) {
      // 1) issue next-chunk global loads (coalesced; latency hidden below)
      float8 fx, f0, f1;
      if (i + 1 < NCHF) {
        const int o = (i + 1) * BKF;
        fx = *(const float8*)(xg + o);
        f0 = *(const float8*)(wg0 + o);
        f1 = *(const float8*)(wg1 + o);
      }
      // 2) compute current chunk from LDS (independent of the loads above)
      const char* s = sm[i & 1];
#pragma unroll
      for (int kk = 0; kk < 4; ++kk) {
        const int sa = ((kk * 4 + t4) ^ axr) << 4;
        const int sb = ((kk * 4 + t4) ^ bxr) << 4;
        short8 ah = *(const short8*)(s + ra + sa);
        short8 al = *(const short8*)(s + ra + 8192 + sa);
        short8 bh = *(const short8*)(s + rb + sb);
        short8 bl = *(const short8*)(s + rb + 16384 + sb);
        acc = __builtin_amdgcn_mfma_f32_16x16x32_bf16(ah, bh, acc, 0, 0, 0);
        acc = __builtin_amdgcn_mfma_f32_16x16x32_bf16(ah, bl, acc, 0, 0, 0);
        acc = __builtin_amdgcn_mfma_f32_16x16x32_bf16(al, bh, acc, 0, 0, 0);
      }
      // 3) convert + write next chunk into the other buffer
      //    (safe: that buffer was last READ before the barrier ending iter i-1)
      if (i + 1 < NCHF) {
        char* d = sm[(i + 1) & 1];
        short8 h, l;
        cvt_split(fx, h, l);
        *(short8*)(d + wx)         = h;  *(short8*)(d + 8192  + wx) = l;
        cvt_split(f0, h, l);
        *(short8*)(d + 16384 + wx) = h;  *(short8*)(d + 32768 + wx) = l;
        cvt_split(f1, h, l);
        *(short8*)(d + 24576 + wx) = h;  *(short8*)(d + 40960 + wx) = l;
      }
      __syncthreads();
    }
  } else {
    // ---------------- bf16 fallback (unexercised; register-direct) --------
    const short* xp = (const short*)xv + (size_t)(r0 + arow) * D_DIM + t4 * 8;
    const short* wp = (const short*)wv + (size_t)brow * D_DIM + t4 * 8;
    for (int k = 0; k < D_DIM; k += 64) {
      short8 a0 = *(const short8*)(xp + k);
      short8 b0 = *(const short8*)(wp + k);
      short8 a1 = *(const short8*)(xp + k + 32);
      short8 b1 = *(const short8*)(wp + k + 32);
      acc = __builtin_amdgcn_mfma_f32_16x16x32_bf16(a0, b0, acc, 0, 0, 0);
      acc = __builtin_amdgcn_mfma_f32_16x16x32_bf16(a1, b1, acc, 0, 0, 0);
    }
  }

  // C/D layout (m89-verified): col = lane&15 (expert), row = (lane>>4)*4 + reg
  {
    const int col   = brow;                        // e0 + lm
    const int rbase = rt * 16 + (t4 << 2);
#pragma unroll
    for (int r = 0; r < 4; ++r) lg[rbase + r][col] = acc[r];
  }
  __syncthreads();

  if (tid < 32) {
    const int row = tid;
    float m1 = -3.4e38f, m2 = -3.4e38f;
    int   i1 = 0, i2 = 0;
    for (int e = 0; e < E_DIM; ++e) {
      float be = isbf ? __bfloat162float(((const __hip_bfloat16*)bv)[e])
                      : ((const float*)bv)[e];
      float l = lg[row][e] + be;
      if (l > m1)      { m2 = m1; i2 = i1; m1 = l; i1 = e; }
      else if (l > m2) { m2 = l;  i2 = e; }
    }
    float s = 0.f;
    for (int e = 0; e < E_DIM; ++e) {
      float be = isbf ? __bfloat162float(((const __hip_bfloat16*)bv)[e])
                      : ((const float*)bv)[e];
      s += expf(lg[row][e] + be - m1);
    }
    const int gr = r0 + row;
    // outputs concatenated flat: [N*2 indices][N*2 weights], all as float32
    out[2 * gr]                  = (float)i1;
    out[2 * gr + 1]              = (float)i2;
    out[2 * N_ROWS + 2 * gr]     = 1.0f / s;                 // exp(m1-m1)/s
    out[2 * N_ROWS + 2 * gr + 1] = expf(m2 - m1) / s;
  }
}

extern "C" void kernel_launch(void* const* d_in, const int* in_sizes, int n_in,
                              void* d_out, int out_size, void* d_ws, size_t ws_size,
                              hipStream_t stream) {
  (void)in_sizes; (void)n_in; (void)out_size; (void)d_ws; (void)ws_size;
  router_kernel<<<dim3(N_ROWS / 32), dim3(512), 0, stream>>>(
      d_in[0], d_in[1], d_in[2], (float*)d_out);
}